// Round 1
// baseline (1840.854 us; speedup 1.0000x reference)
//
#include <hip/hip_runtime.h>
#include <stdint.h>

#define N_PROP 2000
#define NCLS 80
#define NSORT 2048
#define MAXPC 100
#define MAXIMG 300
#define GSORT 8192

// monotone map: float -> uint32 such that u(a) < u(b) <=> a < b
__device__ __forceinline__ uint32_t fkey(float f) {
    uint32_t u = __float_as_uint(f);
    return (u & 0x80000000u) ? ~u : (u | 0x80000000u);
}

__global__ void decode_kernel(const float* __restrict__ deltas,
                              const float* __restrict__ props,
                              float* __restrict__ boxes) {
    int i = blockIdx.x * blockDim.x + threadIdx.x;
    if (i >= N_PROP) return;
    float x1 = props[i*4+0], y1 = props[i*4+1], x2 = props[i*4+2], y2 = props[i*4+3];
    float w = x2 - x1 + 1.0f, h = y2 - y1 + 1.0f;
    float cx = x1 + 0.5f*w,  cy = y1 + 0.5f*h;
    float dx = deltas[i*4+0], dy = deltas[i*4+1], dw = deltas[i*4+2], dh = deltas[i*4+3];
    float pcx = dx*w + cx, pcy = dy*h + cy;
    float pw = expf(dw)*w, ph = expf(dh)*h;
    boxes[i*4+0] = pcx - 0.5f*pw;
    boxes[i*4+1] = pcy - 0.5f*ph;
    boxes[i*4+2] = pcx + 0.5f*pw;
    boxes[i*4+3] = pcy + 0.5f*ph;
}

// one block per class: sort scores desc (stable), greedy NMS, emit top-100
__global__ __launch_bounds__(256) void nms_class_kernel(
        const float* __restrict__ scores,   // [N_PROP][NCLS]
        const float* __restrict__ boxes,    // [N_PROP][4]
        uint32_t* __restrict__ outkey,      // [NCLS][MAXPC]  sortable score keys
        int* __restrict__ outidx) {         // [NCLS][MAXPC]  original proposal idx
    __shared__ uint64_t sk[NSORT];
    __shared__ float bx1[NSORT], by1[NSORT], bx2[NSORT], by2[NSORT], bar[NSORT];
    __shared__ unsigned char supp[NSORT];
    const int c = blockIdx.x;
    const int tid = threadIdx.x;

    for (int i = tid; i < NSORT; i += 256) {
        float s = (i < N_PROP) ? scores[i*NCLS + c] : -__builtin_inff();
        // key: score desc, then original index asc (matches argsort(-s) stability)
        sk[i] = ((uint64_t)fkey(s) << 32) | (uint32_t)(0xFFFFFFFFu - (uint32_t)i);
        supp[i] = 0;
    }
    __syncthreads();

    // bitonic sort, descending by u64 key
    for (int k = 2; k <= NSORT; k <<= 1) {
        for (int j = k >> 1; j > 0; j >>= 1) {
            for (int i = tid; i < NSORT; i += 256) {
                int ixj = i ^ j;
                if (ixj > i) {
                    uint64_t a = sk[i], b = sk[ixj];
                    bool desc = ((i & k) == 0);
                    if (desc ? (a < b) : (a > b)) { sk[i] = b; sk[ixj] = a; }
                }
            }
            __syncthreads();
        }
    }

    // gather boxes into sorted order
    for (int i = tid; i < N_PROP; i += 256) {
        int o = (int)(0xFFFFFFFFu - (uint32_t)(sk[i] & 0xFFFFFFFFu));
        float x1 = boxes[o*4+0], y1 = boxes[o*4+1], x2 = boxes[o*4+2], y2 = boxes[o*4+3];
        bx1[i] = x1; by1[i] = y1; bx2[i] = x2; by2[i] = y2;
        bar[i] = fmaxf(x2-x1, 0.0f) * fmaxf(y2-y1, 0.0f);
    }
    __syncthreads();

    // greedy NMS: sequential over sorted positions, parallel suppression
    for (int i = 0; i < N_PROP; ++i) {
        if (!supp[i]) {
            float x1i = bx1[i], y1i = by1[i], x2i = bx2[i], y2i = by2[i], ai = bar[i];
            for (int j = i + 1 + tid; j < N_PROP; j += 256) {
                if (supp[j]) continue;
                float ix1 = fmaxf(x1i, bx1[j]);
                float iy1 = fmaxf(y1i, by1[j]);
                float ix2 = fminf(x2i, bx2[j]);
                float iy2 = fminf(y2i, by2[j]);
                float inter = fmaxf(ix2-ix1, 0.0f) * fmaxf(iy2-iy1, 0.0f);
                float uni = ai + bar[j] - inter;
                if (inter > 0.7f * uni) supp[j] = 1;  // iou > 0.7, union > 0 always
            }
        }
        __syncthreads();
    }

    // collect first 100 kept (position order == descending score order);
    // if fewer than 100 kept, fill with -inf keys + earliest suppressed indices
    // (matches lax.top_k tie-breaking on the -inf entries)
    if (tid == 0) {
        int cnt = 0;
        for (int i = 0; i < N_PROP && cnt < MAXPC; ++i) {
            if (!supp[i]) {
                outkey[c*MAXPC + cnt] = (uint32_t)(sk[i] >> 32);
                outidx[c*MAXPC + cnt] = (int)(0xFFFFFFFFu - (uint32_t)(sk[i] & 0xFFFFFFFFu));
                cnt++;
            }
        }
        for (int i = 0; i < N_PROP && cnt < MAXPC; ++i) {
            if (supp[i]) {
                outkey[c*MAXPC + cnt] = fkey(-__builtin_inff());
                outidx[c*MAXPC + cnt] = (int)(0xFFFFFFFFu - (uint32_t)(sk[i] & 0xFFFFFFFFu));
                cnt++;
            }
        }
    }
}

// global top-300 over 80*100 entries, then gather boxes + class ids
__global__ __launch_bounds__(1024) void topk_kernel(
        const uint32_t* __restrict__ outkey,
        const int* __restrict__ outidx,
        const float* __restrict__ boxes,
        float* __restrict__ out) {
    __shared__ uint64_t gk[GSORT];
    const int tid = threadIdx.x;
    for (int f = tid; f < GSORT; f += 1024) {
        uint64_t key;
        if (f < NCLS*MAXPC)
            key = ((uint64_t)outkey[f] << 32) | (uint32_t)(0xFFFFFFFFu - (uint32_t)f);
        else
            key = 0;  // pads sort last (real keys have high word >= fkey(-inf) > 0)
        gk[f] = key;
    }
    __syncthreads();
    for (int k = 2; k <= GSORT; k <<= 1) {
        for (int j = k >> 1; j > 0; j >>= 1) {
            for (int i = tid; i < GSORT; i += 1024) {
                int ixj = i ^ j;
                if (ixj > i) {
                    uint64_t a = gk[i], b = gk[ixj];
                    bool desc = ((i & k) == 0);
                    if (desc ? (a < b) : (a > b)) { gk[i] = b; gk[ixj] = a; }
                }
            }
            __syncthreads();
        }
    }
    for (int k = tid; k < MAXIMG; k += 1024) {
        int f = (int)(0xFFFFFFFFu - (uint32_t)(gk[k] & 0xFFFFFFFFu));
        int c = f / MAXPC;
        int pi = outidx[f];
        out[k*4+0] = boxes[pi*4+0];
        out[k*4+1] = boxes[pi*4+1];
        out[k*4+2] = boxes[pi*4+2];
        out[k*4+3] = boxes[pi*4+3];
        out[MAXIMG*4 + k] = (float)c;
    }
}

extern "C" void kernel_launch(void* const* d_in, const int* in_sizes, int n_in,
                              void* d_out, int out_size, void* d_ws, size_t ws_size,
                              hipStream_t stream) {
    const float* deltas = (const float*)d_in[0];   // roi_bboxes_txtytwth [2000,4]
    const float* scores = (const float*)d_in[1];   // roi_score [2000,80]
    const float* props  = (const float*)d_in[2];   // rpn_proposals_bboxes [2000,4]
    float* out = (float*)d_out;                    // 1200 floats boxes + 300 floats cls

    float*    boxes  = (float*)d_ws;                            // 32000 B
    uint32_t* outkey = (uint32_t*)((char*)d_ws + 32000);        // 32000 B
    int*      outidx = (int*)((char*)d_ws + 64000);             // 32000 B

    decode_kernel<<<(N_PROP + 255)/256, 256, 0, stream>>>(deltas, props, boxes);
    nms_class_kernel<<<NCLS, 256, 0, stream>>>(scores, boxes, outkey, outidx);
    topk_kernel<<<1, 1024, 0, stream>>>(outkey, outidx, boxes, out);
}

// Round 2
// 543.224 us; speedup vs baseline: 3.3888x; 3.3888x over previous
//
#include <hip/hip_runtime.h>
#include <stdint.h>

#define N_PROP 2000
#define NCLS 80
#define NSORT 2048
#define MAXPC 100
#define MAXIMG 300
#define NFLAT (NCLS * MAXPC)   // 8000
#define FKEY_NEGINF 0x007FFFFFu

// persistent device scratch (rewritten fully every launch -> deterministic)
__device__ float4   g_boxes[N_PROP];
__device__ uint32_t g_adj[N_PROP * 64];     // bit j of word w: IoU(i, w*32+b) > 0.7
__device__ uint32_t g_outkey[NFLAT];        // sortable score keys, per class sorted desc
__device__ int      g_outidx[NFLAT];        // original proposal indices

// monotone map: float -> uint32 such that u(a) < u(b) <=> a < b
__device__ __forceinline__ uint32_t fkey(float f) {
    uint32_t u = __float_as_uint(f);
    return (u & 0x80000000u) ? ~u : (u | 0x80000000u);
}

__global__ void decode_kernel(const float* __restrict__ deltas,
                              const float* __restrict__ props) {
    int i = blockIdx.x * blockDim.x + threadIdx.x;
    if (i >= N_PROP) return;
    float x1 = props[i*4+0], y1 = props[i*4+1], x2 = props[i*4+2], y2 = props[i*4+3];
    float w = x2 - x1 + 1.0f, h = y2 - y1 + 1.0f;
    float cx = x1 + 0.5f*w,  cy = y1 + 0.5f*h;
    float dx = deltas[i*4+0], dy = deltas[i*4+1], dw = deltas[i*4+2], dh = deltas[i*4+3];
    float pcx = dx*w + cx, pcy = dy*h + cy;
    float pw = expf(dw)*w, ph = expf(dh)*h;
    g_boxes[i] = make_float4(pcx - 0.5f*pw, pcy - 0.5f*ph, pcx + 0.5f*pw, pcy + 0.5f*ph);
}

// 500 blocks x 256 threads: block handles 4 rows; thread (row, word w) packs 32 IoU bits
__global__ __launch_bounds__(256) void adj_kernel() {
    __shared__ float4 bb[N_PROP];           // 32 KB
    const int tid = threadIdx.x;
    for (int j = tid; j < N_PROP; j += 256) bb[j] = g_boxes[j];
    __syncthreads();
    const int row = blockIdx.x * 4 + (tid >> 6);
    const int w   = tid & 63;
    float4 bi = bb[row];
    float ai = fmaxf(bi.z - bi.x, 0.0f) * fmaxf(bi.w - bi.y, 0.0f);
    uint32_t bits = 0u;
    #pragma unroll 8
    for (int b = 0; b < 32; ++b) {
        int j = w * 32 + b;
        if (j < N_PROP) {
            float4 bj = bb[j];
            float aj = fmaxf(bj.z - bj.x, 0.0f) * fmaxf(bj.w - bj.y, 0.0f);
            float ix1 = fmaxf(bi.x, bj.x);
            float iy1 = fmaxf(bi.y, bj.y);
            float ix2 = fminf(bi.z, bj.z);
            float iy2 = fminf(bi.w, bj.w);
            float inter = fmaxf(ix2 - ix1, 0.0f) * fmaxf(iy2 - iy1, 0.0f);
            float uni = ai + aj - inter;
            if (inter > 0.7f * uni) bits |= (1u << b);
        }
    }
    g_adj[row * 64 + w] = bits;
}

#define LOADB(buf, r0base)                                                  \
    _Pragma("unroll")                                                       \
    for (int t = 0; t < 32; ++t) {                                          \
        int r = (r0base) + t;                                               \
        buf[t] = (r < N_PROP) ? g_adj[ord[r] * 64 + lane] : 0u;             \
    }

#define PROCB(buf, r0base)                                                  \
    _Pragma("unroll")                                                       \
    for (int t = 0; t < 32; ++t) {                                          \
        int r = (r0base) + t;                                               \
        if (r < N_PROP) {                                                   \
            int i = (int)ord[r];                                            \
            bool hit = (lane == (i >> 5)) && ((rem >> (i & 31)) & 1u);      \
            unsigned long long m = __ballot(hit);                           \
            if (m == 0ull) { rem |= buf[t]; if (lane == 0) kf[r] = 1; }     \
            else           {                if (lane == 0) kf[r] = 0; }     \
        }                                                                   \
    }

// one block per class: bitonic argsort, bitset greedy NMS (1 wave), collect top-100
__global__ __launch_bounds__(256) void nms_class_kernel(const float* __restrict__ scores) {
    __shared__ uint64_t sk[NSORT];          // 16 KB
    __shared__ uint32_t ord[NSORT];         // 8 KB
    __shared__ unsigned char kf[NSORT];     // 2 KB
    const int c = blockIdx.x;
    const int tid = threadIdx.x;

    for (int i = tid; i < NSORT; i += 256) {
        float s = (i < N_PROP) ? scores[i*NCLS + c] : -__builtin_inff();
        sk[i] = ((uint64_t)fkey(s) << 32) | (uint32_t)(0xFFFFFFFFu - (uint32_t)i);
    }
    __syncthreads();

    // bitonic sort desc by u64 key (score desc, index asc)
    for (int k = 2; k <= NSORT; k <<= 1) {
        for (int j = k >> 1; j > 0; j >>= 1) {
            for (int i = tid; i < NSORT; i += 256) {
                int ixj = i ^ j;
                if (ixj > i) {
                    uint64_t a = sk[i], b = sk[ixj];
                    bool desc = ((i & k) == 0);
                    if (desc ? (a < b) : (a > b)) { sk[i] = b; sk[ixj] = a; }
                }
            }
            __syncthreads();
        }
    }

    for (int i = tid; i < NSORT; i += 256)
        ord[i] = 0xFFFFFFFFu - (uint32_t)(sk[i] & 0xFFFFFFFFu);
    __syncthreads();

    // greedy NMS on one wave: lane w owns u32 word w of the removed-bitset
    if (tid < 64) {
        const int lane = tid;
        uint32_t rem = 0u;
        uint32_t bufA[32], bufB[32];
        LOADB(bufA, 0)
        for (int r0 = 0; r0 < NSORT; r0 += 64) {
            LOADB(bufB, r0 + 32)
            PROCB(bufA, r0)
            LOADB(bufA, r0 + 64)
            PROCB(bufB, r0 + 32)
        }

        // collect first 100 kept (rank order == score desc)
        int base = 0;
        for (int c0 = 0; c0 < N_PROP; c0 += 64) {
            int r = c0 + lane;
            bool k = (r < N_PROP) && kf[r];
            unsigned long long m = __ballot(k);
            int rank = base + __popcll(m & ((1ull << lane) - 1ull));
            if (k && rank < MAXPC) {
                g_outkey[c*MAXPC + rank] = (uint32_t)(sk[r] >> 32);
                g_outidx[c*MAXPC + rank] = (int)ord[r];
            }
            base += __popcll(m);
        }
        // fill with -inf + earliest-suppressed (matches top_k tie-break on -inf)
        if (base < MAXPC) {
            int sbase = 0;
            for (int c0 = 0; c0 < N_PROP; c0 += 64) {
                int r = c0 + lane;
                bool s = (r < N_PROP) && !kf[r];
                unsigned long long m = __ballot(s);
                int rank = base + sbase + __popcll(m & ((1ull << lane) - 1ull));
                if (s && rank < MAXPC) {
                    g_outkey[c*MAXPC + rank] = FKEY_NEGINF;
                    g_outidx[c*MAXPC + rank] = (int)ord[r];
                }
                sbase += __popcll(m);
            }
        }
    }
}

// global top-300: binary-search the 300th-largest score key, compact, sort 512
__global__ __launch_bounds__(1024) void topk_kernel(float* __restrict__ out) {
    __shared__ uint32_t skey[NFLAT];        // 32 KB
    __shared__ uint64_t ck[512];            // 4 KB
    __shared__ int scnt, ccnt;
    const int tid = threadIdx.x;

    for (int f = tid; f < NFLAT; f += 1024) skey[f] = g_outkey[f];
    for (int i = tid; i < 512; i += 1024) ck[i] = 0ull;
    if (tid == 0) ccnt = 0;
    __syncthreads();

    // find V300 = min v with count(skey > v) < 300  (the 300th-largest value)
    uint32_t lo = 0u, hi = 0xFFFFFFFFu;
    while (lo < hi) {
        uint32_t mid = lo + ((hi - lo) >> 1);
        if (tid == 0) scnt = 0;
        __syncthreads();
        int local = 0;
        for (int f = tid; f < NFLAT; f += 1024) local += (skey[f] > mid) ? 1 : 0;
        if (local) atomicAdd(&scnt, local);
        __syncthreads();
        int cgt = scnt;
        __syncthreads();
        if (cgt >= MAXIMG) lo = mid + 1; else hi = mid;
    }

    // compact all entries >= V300 (>= 300 of them; ties sorted out below)
    for (int f = tid; f < NFLAT; f += 1024) {
        if (skey[f] >= lo) {
            int s = atomicAdd(&ccnt, 1);
            if (s < 512) ck[s] = ((uint64_t)skey[f] << 32) | (uint32_t)(0xFFFFFFFFu - (uint32_t)f);
        }
    }
    __syncthreads();

    // bitonic sort 512 desc by u64 key (score desc, flat idx asc); pads(0) sink
    for (int k = 2; k <= 512; k <<= 1) {
        for (int j = k >> 1; j > 0; j >>= 1) {
            for (int i = tid; i < 512; i += 1024) {
                int ixj = i ^ j;
                if (ixj > i) {
                    uint64_t a = ck[i], b = ck[ixj];
                    bool desc = ((i & k) == 0);
                    if (desc ? (a < b) : (a > b)) { ck[i] = b; ck[ixj] = a; }
                }
            }
            __syncthreads();
        }
    }

    for (int k = tid; k < MAXIMG; k += 1024) {
        int f = (int)(0xFFFFFFFFu - (uint32_t)(ck[k] & 0xFFFFFFFFu));
        int pi = g_outidx[f];
        float4 b = g_boxes[pi];
        out[k*4+0] = b.x;
        out[k*4+1] = b.y;
        out[k*4+2] = b.z;
        out[k*4+3] = b.w;
        out[MAXIMG*4 + k] = (float)(f / MAXPC);
    }
}

extern "C" void kernel_launch(void* const* d_in, const int* in_sizes, int n_in,
                              void* d_out, int out_size, void* d_ws, size_t ws_size,
                              hipStream_t stream) {
    const float* deltas = (const float*)d_in[0];   // roi_bboxes_txtytwth [2000,4]
    const float* scores = (const float*)d_in[1];   // roi_score [2000,80]
    const float* props  = (const float*)d_in[2];   // rpn_proposals_bboxes [2000,4]
    float* out = (float*)d_out;                    // 1200 box floats + 300 class floats

    decode_kernel<<<(N_PROP + 255)/256, 256, 0, stream>>>(deltas, props);
    adj_kernel<<<N_PROP/4, 256, 0, stream>>>();
    nms_class_kernel<<<NCLS, 256, 0, stream>>>(scores);
    topk_kernel<<<1, 1024, 0, stream>>>(out);
}

// Round 3
// 90.455 us; speedup vs baseline: 20.3510x; 6.0054x over previous
//
#include <hip/hip_runtime.h>
#include <stdint.h>

#define N_PROP 2000
#define NCLS 80
#define MAXPC 100
#define MAXIMG 300
#define NFLAT (NCLS*MAXPC)   // 8000
#define MAXNB 32
#define CAP 512
#define FKEY_NEGINF 0x007FFFFFu

#define ST_UNDEC 0
#define ST_KEPT 1
#define ST_SUPP 2

// persistent device scratch (fully rewritten every launch -> deterministic)
__device__ float4   g_boxes[N_PROP];
__device__ uint32_t g_adj[N_PROP * 64];     // bitset rows (self-bit excluded)
__device__ int      g_deg[N_PROP];
__device__ int      g_nbr[N_PROP * MAXNB];  // neighbor lists (valid when deg<=MAXNB)
__device__ uint32_t g_outkey[NFLAT];
__device__ int      g_outidx[NFLAT];

// monotone map: float -> uint32 such that u(a) < u(b) <=> a < b
__device__ __forceinline__ uint32_t fkey(float f) {
    uint32_t u = __float_as_uint(f);
    return (u & 0x80000000u) ? ~u : (u | 0x80000000u);
}

__global__ void decode_kernel(const float* __restrict__ deltas,
                              const float* __restrict__ props) {
    int i = blockIdx.x * blockDim.x + threadIdx.x;
    if (i >= N_PROP) return;
    g_deg[i] = 0;   // re-zeroed every launch (adj_kernel accumulates atomically)
    float x1 = props[i*4+0], y1 = props[i*4+1], x2 = props[i*4+2], y2 = props[i*4+3];
    float w = x2 - x1 + 1.0f, h = y2 - y1 + 1.0f;
    float cx = x1 + 0.5f*w,  cy = y1 + 0.5f*h;
    float dx = deltas[i*4+0], dy = deltas[i*4+1], dw = deltas[i*4+2], dh = deltas[i*4+3];
    float pcx = dx*w + cx, pcy = dy*h + cy;
    float pw = expf(dw)*w, ph = expf(dh)*h;
    g_boxes[i] = make_float4(pcx - 0.5f*pw, pcy - 0.5f*ph, pcx + 0.5f*pw, pcy + 0.5f*ph);
}

// 500 blocks x 256: wave per row (4 rows/block); lane packs 32 IoU bits + fills nbr list
__global__ __launch_bounds__(256) void adj_kernel() {
    __shared__ float4 bb[N_PROP];           // 32 KB
    const int tid = threadIdx.x;
    for (int j = tid; j < N_PROP; j += 256) bb[j] = g_boxes[j];
    __syncthreads();
    const int row = blockIdx.x * 4 + (tid >> 6);
    const int lane = tid & 63;
    float4 bi = bb[row];
    float ai = fmaxf(bi.z - bi.x, 0.0f) * fmaxf(bi.w - bi.y, 0.0f);
    uint32_t bits = 0u;
    #pragma unroll 8
    for (int b = 0; b < 32; ++b) {
        int j = lane * 32 + b;
        if (j < N_PROP && j != row) {
            float4 bj = bb[j];
            float aj = fmaxf(bj.z - bj.x, 0.0f) * fmaxf(bj.w - bj.y, 0.0f);
            float ix1 = fmaxf(bi.x, bj.x);
            float iy1 = fmaxf(bi.y, bj.y);
            float ix2 = fminf(bi.z, bj.z);
            float iy2 = fminf(bi.w, bj.w);
            float inter = fmaxf(ix2 - ix1, 0.0f) * fmaxf(iy2 - iy1, 0.0f);
            float uni = ai + aj - inter;
            if (inter > 0.7f * uni) bits |= (1u << b);
        }
    }
    g_adj[row * 64 + lane] = bits;
    uint32_t t = bits;
    while (t) {
        int b = __ffs(t) - 1; t &= t - 1;
        int j = lane * 32 + b;
        int s = atomicAdd(&g_deg[row], 1);
        if (s < MAXNB) g_nbr[row * MAXNB + s] = j;
    }
}

// Block-cooperative (blockDim=256): among {i in [0,n): !state || state[i]==want},
// select top-t by (skey desc, idx asc); leaves them SORTED in cand[0..t-1] as
// (key<<32)|(0xFFFFFFFF-i). Requires 1 <= t <= count(valid), t <= 331.
// Multi-level 8-bit radix select + index-tie resolution -> candidates <= CAP always.
__device__ void select_topt(const uint32_t* skey, const unsigned char* state, int want,
                            int n, int t, uint32_t* hist, uint64_t* cand, int* sh) {
    const int tid = threadIdx.x;
    uint32_t prefix = 0, above = 0, thr = 0, Bi = 0;
    int shift = 24;
    bool tie = false;
    for (;;) {
        for (int b = tid; b < 256; b += 256) hist[b] = 0;
        __syncthreads();
        for (int i = tid; i < n; i += 256) {
            if (!state || state[i] == want) {
                uint32_t k = skey[i];
                if (shift == 24 || (k >> (shift + 8)) == prefix)
                    atomicAdd(&hist[(k >> shift) & 0xFF], 1u);
            }
        }
        __syncthreads();
        // in-place suffix scan: hist[b] = sum_{b' >= b}
        for (int off = 1; off < 256; off <<= 1) {
            uint32_t v = hist[tid] + ((tid + off < 256) ? hist[tid + off] : 0u);
            __syncthreads();
            hist[tid] = v;
            __syncthreads();
        }
        // B = max b with above + suffix(b) >= t (unique crossing; t <= count(valid))
        {
            uint32_t ci = above + hist[tid];
            uint32_t cn = (tid < 255) ? (above + hist[tid + 1]) : 0u;
            if (ci >= (uint32_t)t && ((tid == 255) || cn < (uint32_t)t)) sh[1] = tid;
        }
        __syncthreads();
        int B = sh[1];
        uint32_t nCand = above + hist[B];
        uint32_t nAbove = above + ((B < 255) ? hist[B + 1] : 0u);
        __syncthreads();            // all reads of hist done before reuse
        thr = (prefix << 8) | (uint32_t)B;
        if (nCand <= CAP) break;
        if (shift == 0) {
            // too many exact-key ties at key==thr: take smallest indices
            uint32_t needS = (uint32_t)t - nAbove;      // >= 1
            for (int b = tid; b < 256; b += 256) hist[b] = 0;
            __syncthreads();
            for (int i = tid; i < n; i += 256)
                if ((!state || state[i] == want) && skey[i] == thr)
                    atomicAdd(&hist[i >> 5], 1u);
            __syncthreads();
            // ascending inclusive scan
            for (int off = 1; off < 256; off <<= 1) {
                uint32_t v = hist[tid] + ((tid >= off) ? hist[tid - off] : 0u);
                __syncthreads();
                hist[tid] = v;
                __syncthreads();
            }
            if (hist[tid] >= needS && (tid == 0 || hist[tid - 1] < needS)) sh[1] = tid;
            __syncthreads();
            Bi = (uint32_t)sh[1];
            tie = true;
            __syncthreads();
            break;
        }
        prefix = thr; above = nAbove; shift -= 8;
    }
    // compact candidates into cand[] (zero-padded; pads sink in desc sort)
    for (int i = tid; i < CAP; i += 256) cand[i] = 0ull;
    if (tid == 0) sh[2] = 0;
    __syncthreads();
    for (int i = tid; i < n; i += 256) {
        if (!state || state[i] == want) {
            uint32_t k = skey[i];
            bool take = tie ? (k > thr || (k == thr && (uint32_t)(i >> 5) <= Bi))
                            : ((k >> shift) >= thr);
            if (take) {
                int s = atomicAdd(&sh[2], 1);
                cand[s] = ((uint64_t)k << 32) | (uint32_t)(0xFFFFFFFFu - (uint32_t)i);
            }
        }
    }
    __syncthreads();
    int m = sh[2];
    int sortN = 1; while (sortN < m) sortN <<= 1;
    // bitonic sort desc over sortN (uniform across block)
    for (int k2 = 2; k2 <= sortN; k2 <<= 1) {
        for (int j = k2 >> 1; j > 0; j >>= 1) {
            for (int i = tid; i < sortN; i += 256) {
                int ixj = i ^ j;
                if (ixj > i) {
                    uint64_t a = cand[i], b = cand[ixj];
                    bool desc = ((i & k2) == 0);
                    if (desc ? (a < b) : (a > b)) { cand[i] = b; cand[ixj] = a; }
                }
            }
            __syncthreads();
        }
    }
}

// one block per class: sparse fixpoint NMS (== greedy), then radix-select top-100
__global__ __launch_bounds__(256) void nms_class_kernel(const float* __restrict__ scores) {
    __shared__ uint32_t skey[N_PROP];           // 8 KB
    __shared__ unsigned char state[N_PROP];     // 2 KB
    __shared__ uint16_t sdeg[N_PROP];           // 4 KB
    __shared__ uint32_t hist[256];
    __shared__ uint64_t cand[CAP];              // 4 KB
    __shared__ int sh[4];
    __shared__ int s_changed, s_kept;
    const int c = blockIdx.x, tid = threadIdx.x;

    for (int i = tid; i < N_PROP; i += 256) {
        skey[i] = fkey(scores[i * NCLS + c]);
        int d = g_deg[i];
        sdeg[i] = (uint16_t)(d > 65535 ? 65535 : d);
        state[i] = (d == 0) ? ST_KEPT : ST_UNDEC;
    }
    if (tid == 0) s_changed = 0;
    __syncthreads();

    // fixpoint: keep[i] <=> no adjacent better j with keep[j]  (== greedy NMS)
    for (;;) {
        for (int i = tid; i < N_PROP; i += 256) {
            if (state[i] != ST_UNDEC) continue;
            uint32_t ki = skey[i];
            int deg = sdeg[i];
            bool anyKept = false, anyUndec = false;
            if (deg <= MAXNB) {
                for (int nn = 0; nn < deg; ++nn) {
                    int j = g_nbr[i * MAXNB + nn];
                    uint32_t kj = skey[j];
                    if (kj > ki || (kj == ki && j < i)) {
                        unsigned char stj = state[j];
                        if (stj == ST_KEPT) anyKept = true;
                        else if (stj == ST_UNDEC) anyUndec = true;
                    }
                }
            } else {
                for (int w = 0; w < 64; ++w) {
                    uint32_t bits = g_adj[i * 64 + w];
                    while (bits) {
                        int b = __ffs(bits) - 1; bits &= bits - 1;
                        int j = w * 32 + b;
                        uint32_t kj = skey[j];
                        if (kj > ki || (kj == ki && j < i)) {
                            unsigned char stj = state[j];
                            if (stj == ST_KEPT) anyKept = true;
                            else if (stj == ST_UNDEC) anyUndec = true;
                        }
                    }
                }
            }
            if (anyKept)       { state[i] = ST_SUPP; s_changed = 1; }
            else if (!anyUndec){ state[i] = ST_KEPT; s_changed = 1; }
        }
        __syncthreads();
        int ch = s_changed;
        __syncthreads();
        if (!ch) break;
        if (tid == 0) s_changed = 0;
        __syncthreads();
    }

    if (tid == 0) s_kept = 0;
    __syncthreads();
    {
        int local = 0;
        for (int i = tid; i < N_PROP; i += 256) local += (state[i] == ST_KEPT) ? 1 : 0;
        if (local) atomicAdd(&s_kept, local);
    }
    __syncthreads();
    const int kept = s_kept;

    const int t1 = kept < MAXPC ? kept : MAXPC;   // kept >= 1 always (best vert kept)
    select_topt(skey, state, ST_KEPT, N_PROP, t1, hist, cand, sh);
    for (int r = tid; r < t1; r += 256) {
        uint64_t e = cand[r];
        g_outkey[c * MAXPC + r] = (uint32_t)(e >> 32);
        g_outidx[c * MAXPC + r] = (int)(0xFFFFFFFFu - (uint32_t)e);
    }
    if (kept < MAXPC) {
        __syncthreads();            // cand reads done before reuse
        const int t2 = MAXPC - kept;    // suppressed count = 2000-kept >= t2
        select_topt(skey, state, ST_SUPP, N_PROP, t2, hist, cand, sh);
        for (int r = tid; r < t2; r += 256) {
            uint64_t e = cand[r];
            g_outkey[c * MAXPC + kept + r] = FKEY_NEGINF;
            g_outidx[c * MAXPC + kept + r] = (int)(0xFFFFFFFFu - (uint32_t)e);
        }
    }
}

// global top-300 over the 8000 per-class entries, then gather boxes + class ids
__global__ __launch_bounds__(256) void topk_kernel(float* __restrict__ out) {
    __shared__ uint32_t skey[NFLAT];            // 32 KB
    __shared__ uint32_t hist[256];
    __shared__ uint64_t cand[CAP];
    __shared__ int sh[4];
    const int tid = threadIdx.x;
    for (int f = tid; f < NFLAT; f += 256) skey[f] = g_outkey[f];
    __syncthreads();
    select_topt(skey, nullptr, 0, NFLAT, MAXIMG, hist, cand, sh);
    for (int r = tid; r < MAXIMG; r += 256) {
        uint64_t e = cand[r];
        int f = (int)(0xFFFFFFFFu - (uint32_t)e);
        int pi = g_outidx[f];
        float4 b = g_boxes[pi];
        out[r*4+0] = b.x;
        out[r*4+1] = b.y;
        out[r*4+2] = b.z;
        out[r*4+3] = b.w;
        out[MAXIMG*4 + r] = (float)(f / MAXPC);
    }
}

extern "C" void kernel_launch(void* const* d_in, const int* in_sizes, int n_in,
                              void* d_out, int out_size, void* d_ws, size_t ws_size,
                              hipStream_t stream) {
    const float* deltas = (const float*)d_in[0];   // roi_bboxes_txtytwth [2000,4]
    const float* scores = (const float*)d_in[1];   // roi_score [2000,80]
    const float* props  = (const float*)d_in[2];   // rpn_proposals_bboxes [2000,4]
    float* out = (float*)d_out;                    // 1200 box floats + 300 class floats

    decode_kernel<<<(N_PROP + 255)/256, 256, 0, stream>>>(deltas, props);
    adj_kernel<<<N_PROP/4, 256, 0, stream>>>();
    nms_class_kernel<<<NCLS, 256, 0, stream>>>(scores);
    topk_kernel<<<1, 256, 0, stream>>>(out);
}